// Round 1
// baseline (318.712 us; speedup 1.0000x reference)
//
#include <hip/hip_runtime.h>
#include <math.h>

#define BATCH 32
#define LL    4096
#define FDIM  128
#define NLEV  12
#define EPSF  1e-5f

// ws layout (float offsets)
#define OFF_CQ   0         // 4096
#define OFF_CK   4096      // 4096
#define OFF_D    8192      // 2 (dq, dk)
#define OFF_QSUM 8320      // 32*128
#define OFF_KSUM 12416     // 32*128
#define OFF_S1   16512     // 32*128
#define OFF_S1Q  20608     // 32*128
#define OFF_S2   24704     // 32*128
#define OFF_S2Q  28800     // 32*128
#define OFF_ATT  32896     // 32*128*128
#define OFF_X2   557184    // 32*4096*128

// ---------------------------------------------------------------- coeff
// wave collapses to q[b,f] = sum_l cq[l]*x[b,l,f] + dq  (bit_i(l), LSB first)
__global__ void coeff_kernel(const float* __restrict__ qw, const float* __restrict__ qb,
                             const float* __restrict__ kw, const float* __restrict__ kb,
                             float* __restrict__ ws) {
    int l = blockIdx.x * 256 + threadIdx.x;
    float cq = 1.f, ck = 1.f;
#pragma unroll
    for (int i = 0; i < NLEV; i++) {
        int bit = (l >> i) & 1;
        cq *= qw[2 * i + bit];
        ck *= kw[2 * i + bit];
    }
    ws[OFF_CQ + l] = cq;
    ws[OFF_CK + l] = ck;
    if (l == 0) {
        float dq = 0.f, dk = 0.f;
        for (int i = 0; i < NLEV; i++) {
            dq = (qw[2 * i] + qw[2 * i + 1]) * dq + qb[i];
            dk = (kw[2 * i] + kw[2 * i + 1]) * dk + kb[i];
        }
        ws[OFF_D]     = dq;
        ws[OFF_D + 1] = dk;
    }
}

// ---------------------------------------------------------------- q/k reduce
// grid (32 chunks of 128 rows, 32 batch), block 256
__global__ void qk_kernel(const float* __restrict__ x, float* __restrict__ ws) {
    int b  = blockIdx.y;
    int c0 = blockIdx.x * 128;
    int f  = threadIdx.x & 127;
    int h  = threadIdx.x >> 7;
    const float* Xb = x + (size_t)b * LL * FDIM;
    float qa = 0.f, ka = 0.f;
    for (int it = 0; it < 64; it++) {
        int l = c0 + it * 2 + h;
        float v = Xb[l * FDIM + f];
        qa += ws[OFF_CQ + l] * v;
        ka += ws[OFF_CK + l] * v;
    }
    __shared__ float red[256];
    red[threadIdx.x] = qa;
    __syncthreads();
    if (threadIdx.x < 128)
        atomicAdd(&ws[OFF_QSUM + b * FDIM + f], red[threadIdx.x] + red[threadIdx.x + 128]);
    __syncthreads();
    red[threadIdx.x] = ka;
    __syncthreads();
    if (threadIdx.x < 128)
        atomicAdd(&ws[OFF_KSUM + b * FDIM + f], red[threadIdx.x] + red[threadIdx.x + 128]);
}

// ---------------------------------------------------------------- softmax rows
// grid 32*128 (one block per (b,f) row), block 128
__global__ void att_kernel(float* __restrict__ ws) {
    int b = blockIdx.x >> 7;
    int f = blockIdx.x & 127;
    int g = threadIdx.x;
    float dq = ws[OFF_D], dk = ws[OFF_D + 1];
    float qf = ws[OFF_QSUM + b * FDIM + f] + dq;
    float kg = ws[OFF_KSUM + b * FDIM + g] + dk;
    float s  = qf * kg * 0.08838834764831845f;  // 1/sqrt(128)
    __shared__ float red[128];
    red[g] = s;
    __syncthreads();
    for (int off = 64; off; off >>= 1) {
        if (g < off) red[g] = fmaxf(red[g], red[g + off]);
        __syncthreads();
    }
    float m = red[0];
    __syncthreads();
    float e = expf(s - m);
    red[g] = e;
    __syncthreads();
    for (int off = 64; off; off >>= 1) {
        if (g < off) red[g] += red[g + off];
        __syncthreads();
    }
    float inv = 1.f / red[0];
    ws[OFF_ATT + (size_t)b * FDIM * FDIM + f * FDIM + g] = e * inv;
}

// ---------------------------------------------------------------- GEMM1: X2 = X + X@A
// grid (64 row-tiles, 2 col-tiles, 32 batch), block 256, 4x4 acc/thread
__global__ __launch_bounds__(256, 2) void gemm1_kernel(const float* __restrict__ x,
                                                       const float* __restrict__ attb,
                                                       float* __restrict__ x2) {
    __shared__ float Xs[64][129];
    __shared__ float Bs[128][68];
    const int b  = blockIdx.z;
    const int r0 = blockIdx.x * 64;
    const int g0 = blockIdx.y * 64;
    const float* A  = attb + (size_t)b * FDIM * FDIM;
    const float* Xg = x + (size_t)b * LL * FDIM;
    float* X2 = x2 + (size_t)b * LL * FDIM;
    const int tid = threadIdx.x;

#pragma unroll
    for (int i = 0; i < 32; i++) {           // Xs: 64x128 coalesced
        int idx = tid + i * 256;
        int r = idx >> 7, c = idx & 127;
        Xs[r][c] = Xg[(r0 + r) * FDIM + c];
    }
#pragma unroll
    for (int i = 0; i < 32; i++) {           // Bs[f][gg] = A[f][g0+gg], coalesced over gg
        int idx = tid + i * 256;
        int f = idx >> 6, gg = idx & 63;
        Bs[f][gg] = A[f * FDIM + g0 + gg];
    }
    __syncthreads();

    const int tx = tid & 15;   // cols g0 + tx*4 + j
    const int ty = tid >> 4;   // rows ty*4 + i
    float acc[4][4] = {};
#pragma unroll 8
    for (int f = 0; f < 128; f++) {
        float xf[4], bf[4];
#pragma unroll
        for (int i = 0; i < 4; i++) xf[i] = Xs[ty * 4 + i][f];
#pragma unroll
        for (int j = 0; j < 4; j++) bf[j] = Bs[f][tx * 4 + j];
#pragma unroll
        for (int i = 0; i < 4; i++)
#pragma unroll
            for (int j = 0; j < 4; j++) acc[i][j] += xf[i] * bf[j];
    }
#pragma unroll
    for (int i = 0; i < 4; i++) {
        int r = ty * 4 + i;
        float4 v;
        v.x = Xs[r][g0 + tx * 4 + 0] + acc[i][0];
        v.y = Xs[r][g0 + tx * 4 + 1] + acc[i][1];
        v.z = Xs[r][g0 + tx * 4 + 2] + acc[i][2];
        v.w = Xs[r][g0 + tx * 4 + 3] + acc[i][3];
        *reinterpret_cast<float4*>(&X2[(r0 + r) * FDIM + g0 + tx * 4]) = v;
    }
}

// ---------------------------------------------------------------- column stats (sum, sumsq) over L
// grid (16 chunks of 256 rows, 32 batch), block 256
__global__ void stats_kernel(const float* __restrict__ P, float* __restrict__ sum,
                             float* __restrict__ sumsq) {
    int b  = blockIdx.y;
    int c0 = blockIdx.x * 256;
    int f  = threadIdx.x & 127;
    int h  = threadIdx.x >> 7;
    const float* Pb = P + (size_t)b * LL * FDIM;
    float s = 0.f, sq = 0.f;
    for (int it = 0; it < 128; it++) {
        int l = c0 + it * 2 + h;
        float v = Pb[l * FDIM + f];
        s += v;
        sq += v * v;
    }
    __shared__ float red[256];
    red[threadIdx.x] = s;
    __syncthreads();
    if (threadIdx.x < 128)
        atomicAdd(&sum[b * FDIM + f], red[threadIdx.x] + red[threadIdx.x + 128]);
    __syncthreads();
    red[threadIdx.x] = sq;
    __syncthreads();
    if (threadIdx.x < 128)
        atomicAdd(&sumsq[b * FDIM + f], red[threadIdx.x] + red[threadIdx.x + 128]);
}

// ---------------------------------------------------------------- GEMM2: z = y + y@Wff^T + ffb, y = in1(X2)
__global__ __launch_bounds__(256, 2) void gemm2_kernel(const float* __restrict__ ffw,
                                                       const float* __restrict__ ffb,
                                                       const float* __restrict__ gamma,
                                                       const float* __restrict__ beta,
                                                       const float* __restrict__ s1,
                                                       const float* __restrict__ s1q,
                                                       const float* __restrict__ x2,
                                                       float* __restrict__ out) {
    __shared__ float Xs[64][129];
    __shared__ float Bs[128][68];
    __shared__ float a1s[128], b1s[128];
    const int b  = blockIdx.z;
    const int r0 = blockIdx.x * 64;
    const int g0 = blockIdx.y * 64;
    const int tid = threadIdx.x;

    if (tid < 128) {
        float s    = s1[b * FDIM + tid];
        float sq   = s1q[b * FDIM + tid];
        float mean = s * (1.f / LL);
        float var  = sq * (1.f / LL) - mean * mean;
        float a    = gamma[tid] * rsqrtf(var + EPSF);
        a1s[tid]   = a;
        b1s[tid]   = beta[tid] - mean * a;
    }
    __syncthreads();

    const float* X2 = x2 + (size_t)b * LL * FDIM;
#pragma unroll
    for (int i = 0; i < 32; i++) {           // Xs = y (instance-norm fused)
        int idx = tid + i * 256;
        int r = idx >> 7, c = idx & 127;
        Xs[r][c] = a1s[c] * X2[(r0 + r) * FDIM + c] + b1s[c];
    }
#pragma unroll
    for (int i = 0; i < 32; i++) {           // Bs[f][gg] = ffw[g0+gg][f] (transpose-load, coalesced read)
        int idx = tid + i * 256;
        int gg = idx >> 7, f = idx & 127;
        Bs[f][gg] = ffw[(g0 + gg) * FDIM + f];
    }
    __syncthreads();

    const int tx = tid & 15;
    const int ty = tid >> 4;
    float acc[4][4] = {};
#pragma unroll 8
    for (int f = 0; f < 128; f++) {
        float xf[4], bf[4];
#pragma unroll
        for (int i = 0; i < 4; i++) xf[i] = Xs[ty * 4 + i][f];
#pragma unroll
        for (int j = 0; j < 4; j++) bf[j] = Bs[f][tx * 4 + j];
#pragma unroll
        for (int i = 0; i < 4; i++)
#pragma unroll
            for (int j = 0; j < 4; j++) acc[i][j] += xf[i] * bf[j];
    }
    float* Ob = out + (size_t)b * LL * FDIM;
#pragma unroll
    for (int i = 0; i < 4; i++) {
        int r = ty * 4 + i;
        float4 v;
        v.x = Xs[r][g0 + tx * 4 + 0] + acc[i][0] + ffb[g0 + tx * 4 + 0];
        v.y = Xs[r][g0 + tx * 4 + 1] + acc[i][1] + ffb[g0 + tx * 4 + 1];
        v.z = Xs[r][g0 + tx * 4 + 2] + acc[i][2] + ffb[g0 + tx * 4 + 2];
        v.w = Xs[r][g0 + tx * 4 + 3] + acc[i][3] + ffb[g0 + tx * 4 + 3];
        *reinterpret_cast<float4*>(&Ob[(r0 + r) * FDIM + g0 + tx * 4]) = v;
    }
}

// ---------------------------------------------------------------- final in-place instance norm
__global__ void final_kernel(const float* __restrict__ gamma, const float* __restrict__ beta,
                             const float* __restrict__ s2, const float* __restrict__ s2q,
                             float* __restrict__ out) {
    size_t idx4 = ((size_t)blockIdx.x * 256 + threadIdx.x) * 4;
    int b  = (int)(idx4 >> 19);      // L*F = 2^19
    int g0 = (int)(idx4 & 127);
    float4 v = *reinterpret_cast<float4*>(&out[idx4]);
    float r[4] = {v.x, v.y, v.z, v.w};
#pragma unroll
    for (int j = 0; j < 4; j++) {
        int g     = g0 + j;
        float mean = s2[b * FDIM + g] * (1.f / LL);
        float var  = s2q[b * FDIM + g] * (1.f / LL) - mean * mean;
        float a    = gamma[g] * rsqrtf(var + EPSF);
        r[j]       = a * (r[j] - mean) + beta[g];
    }
    v.x = r[0]; v.y = r[1]; v.z = r[2]; v.w = r[3];
    *reinterpret_cast<float4*>(&out[idx4]) = v;
}

extern "C" void kernel_launch(void* const* d_in, const int* in_sizes, int n_in,
                              void* d_out, int out_size, void* d_ws, size_t ws_size,
                              hipStream_t stream) {
    const float* x     = (const float*)d_in[0];
    const float* q_w   = (const float*)d_in[1];
    const float* q_b   = (const float*)d_in[2];
    const float* k_w   = (const float*)d_in[3];
    const float* k_b   = (const float*)d_in[4];
    const float* ff_w  = (const float*)d_in[5];
    const float* ff_b  = (const float*)d_in[6];
    const float* gamma = (const float*)d_in[7];
    const float* beta  = (const float*)d_in[8];
    float* out = (float*)d_out;
    float* ws  = (float*)d_ws;

    // zero the accumulator region [QSUM .. ATT)
    hipMemsetAsync((char*)d_ws + (size_t)OFF_QSUM * 4, 0,
                   (size_t)(OFF_ATT - OFF_QSUM) * 4, stream);

    coeff_kernel<<<16, 256, 0, stream>>>(q_w, q_b, k_w, k_b, ws);
    qk_kernel<<<dim3(32, 32), 256, 0, stream>>>(x, ws);
    att_kernel<<<BATCH * FDIM, 128, 0, stream>>>(ws);
    gemm1_kernel<<<dim3(64, 2, BATCH), 256, 0, stream>>>(x, ws + OFF_ATT, ws + OFF_X2);
    stats_kernel<<<dim3(16, BATCH), 256, 0, stream>>>(ws + OFF_X2, ws + OFF_S1, ws + OFF_S1Q);
    gemm2_kernel<<<dim3(64, 2, BATCH), 256, 0, stream>>>(ff_w, ff_b, gamma, beta,
                                                         ws + OFF_S1, ws + OFF_S1Q,
                                                         ws + OFF_X2, out);
    stats_kernel<<<dim3(16, BATCH), 256, 0, stream>>>(out, ws + OFF_S2, ws + OFF_S2Q);
    final_kernel<<<out_size / 1024, 256, 0, stream>>>(gamma, beta,
                                                      ws + OFF_S2, ws + OFF_S2Q, out);
}

// Round 2
// 214.382 us; speedup vs baseline: 1.4867x; 1.4867x over previous
//
#include <hip/hip_runtime.h>
#include <math.h>

typedef __attribute__((ext_vector_type(8))) short bf16x8;
typedef __attribute__((ext_vector_type(4))) float f32x4;

#define BATCH 32
#define LL    4096
#define FDIM  128
#define NLEV  12
#define EPSF  1e-5f

// ws layout (float offsets)
#define OFF_QSUM 0          // 32*128
#define OFF_KSUM 4096
#define OFF_S1   8192
#define OFF_S1Q  12288
#define OFF_S2   16384
#define OFF_S2Q  20480
#define OFF_CQ   24576      // 4096
#define OFF_CK   28672      // 4096
#define OFF_D    32768      // 2
#define OFF_ATTT 32896      // bf16[32][128][128] = 262144 floats
#define OFF_X2   295040     // fp32[32][4096][128]

__device__ inline unsigned short bfr(float f) {   // fp32 -> bf16 RTNE
    union { float f; unsigned u; } v; v.f = f;
    unsigned r = v.u + 0x7FFF + ((v.u >> 16) & 1);
    return (unsigned short)(r >> 16);
}

// ---------------------------------------------------------------- coeff
__global__ void coeff_kernel(const float* __restrict__ qw, const float* __restrict__ qb,
                             const float* __restrict__ kw, const float* __restrict__ kb,
                             float* __restrict__ ws) {
    int l = blockIdx.x * 256 + threadIdx.x;
    float cq = 1.f, ck = 1.f;
#pragma unroll
    for (int i = 0; i < NLEV; i++) {
        int bit = (l >> i) & 1;
        cq *= qw[2 * i + bit];
        ck *= kw[2 * i + bit];
    }
    ws[OFF_CQ + l] = cq;
    ws[OFF_CK + l] = ck;
    if (l == 0) {
        float dq = 0.f, dk = 0.f;
        for (int i = 0; i < NLEV; i++) {
            dq = (qw[2 * i] + qw[2 * i + 1]) * dq + qb[i];
            dk = (kw[2 * i] + kw[2 * i + 1]) * dk + kb[i];
        }
        ws[OFF_D]     = dq;
        ws[OFF_D + 1] = dk;
    }
}

// ---------------------------------------------------------------- q/k reduce (float4)
// grid (16, 32), block 256 — 256 rows per block
__global__ void qk_kernel(const float* __restrict__ x, float* __restrict__ ws) {
    int b  = blockIdx.y;
    int c0 = blockIdx.x * 256;
    int f4 = (threadIdx.x & 31) * 4;
    int rh = threadIdx.x >> 5;               // 0..7
    const float* Xb = x + (size_t)b * LL * FDIM;
    float4 qa = {0, 0, 0, 0}, ka = {0, 0, 0, 0};
    for (int it = 0; it < 32; it++) {
        int l = c0 + it * 8 + rh;
        float4 v = *(const float4*)&Xb[l * FDIM + f4];
        float cq = ws[OFF_CQ + l], ck = ws[OFF_CK + l];
        qa.x += cq * v.x; qa.y += cq * v.y; qa.z += cq * v.z; qa.w += cq * v.w;
        ka.x += ck * v.x; ka.y += ck * v.y; ka.z += ck * v.z; ka.w += ck * v.w;
    }
    __shared__ float redq[8][132];
    __shared__ float redk[8][132];
    *(float4*)&redq[rh][f4] = qa;
    *(float4*)&redk[rh][f4] = ka;
    __syncthreads();
    if (threadIdx.x < 128) {
        int f = threadIdx.x;
        float sq = 0.f, sk = 0.f;
#pragma unroll
        for (int r = 0; r < 8; r++) { sq += redq[r][f]; sk += redk[r][f]; }
        atomicAdd(&ws[OFF_QSUM + b * FDIM + f], sq);
        atomicAdd(&ws[OFF_KSUM + b * FDIM + f], sk);
    }
}

// ---------------------------------------------------------------- attention -> (I+A)^T bf16
// grid 32 (batch), block 128 (f). Scores are rank-1: s[f][g] = qf*kg.
__global__ void att_kernel(float* __restrict__ ws, unsigned short* __restrict__ attT) {
    __shared__ float tile[128][128];
    __shared__ float ks[128];
    __shared__ float inv[128];
    __shared__ float red[128];
    int b = blockIdx.x;
    int f = threadIdx.x;
    float dq = ws[OFF_D], dk = ws[OFF_D + 1];
    float qf = (ws[OFF_QSUM + b * FDIM + f] + dq) * 0.08838834764831845f;
    float kf = ws[OFF_KSUM + b * FDIM + f] + dk;
    ks[f] = kf;
    red[f] = kf; __syncthreads();
    for (int o = 64; o; o >>= 1) { if (f < o) red[f] = fmaxf(red[f], red[f + o]); __syncthreads(); }
    float kmax = red[0]; __syncthreads();
    red[f] = kf; __syncthreads();
    for (int o = 64; o; o >>= 1) { if (f < o) red[f] = fminf(red[f], red[f + o]); __syncthreads(); }
    float kmin = red[0]; __syncthreads();

    float m = (qf >= 0.f) ? qf * kmax : qf * kmin;   // rowwise max of qf*kg
    float s = 0.f;
    for (int g = 0; g < 128; g++) {
        float e = __expf(qf * ks[g] - m);
        tile[g][f] = e;                              // transposed store, conflict-free
        s += e;
    }
    inv[f] = 1.f / s;
    __syncthreads();
    unsigned short* ab = attT + (size_t)b * FDIM * FDIM;
    for (int g = 0; g < 128; g++) {
        float v = tile[g][f] * inv[f];
        if (g == f) v += 1.f;                        // fold residual identity
        ab[g * FDIM + f] = bfr(v);
    }
}

// ---------------------------------------------------------------- GEMM1 (MFMA): X2 = X @ (I+A), fused stats1
// grid (64, 32), block 256 (4 waves); wave w: rows w*16..+15, 8 col tiles
__global__ __launch_bounds__(256) void gemm1_kernel(const float* __restrict__ x,
                                                    const unsigned short* __restrict__ attT,
                                                    float* __restrict__ x2,
                                                    float* __restrict__ s1,
                                                    float* __restrict__ s1q) {
    __shared__ __align__(16) unsigned short Xs[64][136];
    __shared__ __align__(16) unsigned short Bs[128][136];
    __shared__ float scratch[256];                   // csum[128], csq[128]
    const int b   = blockIdx.y;
    const int r0  = blockIdx.x * 64;
    const int tid = threadIdx.x;
    const float* Xg = x + (size_t)b * LL * FDIM + (size_t)r0 * FDIM;
    const unsigned short* Ag = attT + (size_t)b * FDIM * FDIM;

#pragma unroll
    for (int i = 0; i < 8; i++) {                    // stage X fp32 -> bf16
        int idx4 = (tid + i * 256) * 4;
        int r = idx4 >> 7, c = idx4 & 127;
        float4 v = *(const float4*)&Xg[r * FDIM + c];
        ushort4 h; h.x = bfr(v.x); h.y = bfr(v.y); h.z = bfr(v.z); h.w = bfr(v.w);
        *(ushort4*)&Xs[r][c] = h;
    }
#pragma unroll
    for (int i = 0; i < 16; i++) {                   // stage (I+A)^T bf16
        int idx4 = (tid + i * 256) * 4;
        int g = idx4 >> 7, c = idx4 & 127;
        *(ushort4*)&Bs[g][c] = *(const ushort4*)&Ag[g * FDIM + c];
    }
    scratch[tid] = 0.f;
    __syncthreads();

    const int wave = tid >> 6, lane = tid & 63;
    const int l15 = lane & 15, quad = lane >> 4;
    const int rowA = wave * 16 + l15;

    f32x4 acc[8];
#pragma unroll
    for (int t = 0; t < 8; t++) acc[t] = (f32x4){0.f, 0.f, 0.f, 0.f};
#pragma unroll
    for (int k0 = 0; k0 < 128; k0 += 32) {
        bf16x8 a = *(const bf16x8*)&Xs[rowA][k0 + quad * 8];
#pragma unroll
        for (int t = 0; t < 8; t++) {
            bf16x8 bb = *(const bf16x8*)&Bs[t * 16 + l15][k0 + quad * 8];
            acc[t] = __builtin_amdgcn_mfma_f32_16x16x32_bf16(a, bb, acc[t], 0, 0, 0);
        }
    }

    float* X2 = x2 + (size_t)b * LL * FDIM + (size_t)r0 * FDIM;
    float* csum = scratch;
    float* csq  = scratch + 128;
#pragma unroll
    for (int t = 0; t < 8; t++) {
        int col = t * 16 + l15;
        float s = 0.f, q = 0.f;
#pragma unroll
        for (int reg = 0; reg < 4; reg++) {
            float v = acc[t][reg];
            X2[(wave * 16 + quad * 4 + reg) * FDIM + col] = v;
            s += v; q += v * v;
        }
        s += __shfl_xor(s, 16, 64); s += __shfl_xor(s, 32, 64);
        q += __shfl_xor(q, 16, 64); q += __shfl_xor(q, 32, 64);
        if (quad == 0) { atomicAdd(&csum[col], s); atomicAdd(&csq[col], q); }
    }
    __syncthreads();
    if (tid < 128) {
        atomicAdd(&s1 [b * FDIM + tid], csum[tid]);
        atomicAdd(&s1q[b * FDIM + tid], csq[tid]);
    }
}

// ---------------------------------------------------------------- GEMM2 (MFMA): out = norm1(X2) @ (I+W^T) + ffb, fused stats2
__global__ __launch_bounds__(256) void gemm2_kernel(const float* __restrict__ ffw,
                                                    const float* __restrict__ ffb,
                                                    const float* __restrict__ gamma,
                                                    const float* __restrict__ beta,
                                                    const float* __restrict__ s1,
                                                    const float* __restrict__ s1q,
                                                    const float* __restrict__ x2,
                                                    float* __restrict__ out,
                                                    float* __restrict__ s2,
                                                    float* __restrict__ s2q) {
    __shared__ __align__(16) unsigned short Xs[64][136];
    __shared__ __align__(16) unsigned short Bs[128][136];
    __shared__ float scratch[256];                   // a1/b1 during staging, csum/csq in epilogue
    __shared__ float ffbs[128];
    const int b   = blockIdx.y;
    const int r0  = blockIdx.x * 64;
    const int tid = threadIdx.x;

    if (tid < 128) {
        float s    = s1[b * FDIM + tid];
        float sq   = s1q[b * FDIM + tid];
        float mean = s * (1.f / LL);
        float var  = sq * (1.f / LL) - mean * mean;
        float a    = gamma[tid] * rsqrtf(var + EPSF);
        scratch[tid]       = a;
        scratch[128 + tid] = beta[tid] - mean * a;
        ffbs[tid] = ffb[tid];
    }
    __syncthreads();

    const float* X2g = x2 + (size_t)b * LL * FDIM + (size_t)r0 * FDIM;
#pragma unroll
    for (int i = 0; i < 8; i++) {                    // stage y = norm1(X2) -> bf16
        int idx4 = (tid + i * 256) * 4;
        int r = idx4 >> 7, c = idx4 & 127;
        float4 v = *(const float4*)&X2g[r * FDIM + c];
        ushort4 h;
        h.x = bfr(scratch[c + 0] * v.x + scratch[128 + c + 0]);
        h.y = bfr(scratch[c + 1] * v.y + scratch[128 + c + 1]);
        h.z = bfr(scratch[c + 2] * v.z + scratch[128 + c + 2]);
        h.w = bfr(scratch[c + 3] * v.w + scratch[128 + c + 3]);
        *(ushort4*)&Xs[r][c] = h;
    }
#pragma unroll
    for (int i = 0; i < 16; i++) {                   // stage I + W^T: Bs[g][f] = W[g][f] + (f==g)
        int idx4 = (tid + i * 256) * 4;
        int g = idx4 >> 7, c = idx4 & 127;
        float4 w = *(const float4*)&ffw[g * FDIM + c];
        if (g == c + 0) w.x += 1.f;
        if (g == c + 1) w.y += 1.f;
        if (g == c + 2) w.z += 1.f;
        if (g == c + 3) w.w += 1.f;
        ushort4 h; h.x = bfr(w.x); h.y = bfr(w.y); h.z = bfr(w.z); h.w = bfr(w.w);
        *(ushort4*)&Bs[g][c] = h;
    }
    __syncthreads();                                 // a1/b1 dead after this
    scratch[tid] = 0.f;
    __syncthreads();

    const int wave = tid >> 6, lane = tid & 63;
    const int l15 = lane & 15, quad = lane >> 4;
    const int rowA = wave * 16 + l15;

    f32x4 acc[8];
#pragma unroll
    for (int t = 0; t < 8; t++) acc[t] = (f32x4){0.f, 0.f, 0.f, 0.f};
#pragma unroll
    for (int k0 = 0; k0 < 128; k0 += 32) {
        bf16x8 a = *(const bf16x8*)&Xs[rowA][k0 + quad * 8];
#pragma unroll
        for (int t = 0; t < 8; t++) {
            bf16x8 bb = *(const bf16x8*)&Bs[t * 16 + l15][k0 + quad * 8];
            acc[t] = __builtin_amdgcn_mfma_f32_16x16x32_bf16(a, bb, acc[t], 0, 0, 0);
        }
    }

    float* Ob = out + (size_t)b * LL * FDIM + (size_t)r0 * FDIM;
    float* csum = scratch;
    float* csq  = scratch + 128;
#pragma unroll
    for (int t = 0; t < 8; t++) {
        int col = t * 16 + l15;
        float fb = ffbs[col];
        float s = 0.f, q = 0.f;
#pragma unroll
        for (int reg = 0; reg < 4; reg++) {
            float v = acc[t][reg] + fb;
            Ob[(wave * 16 + quad * 4 + reg) * FDIM + col] = v;
            s += v; q += v * v;
        }
        s += __shfl_xor(s, 16, 64); s += __shfl_xor(s, 32, 64);
        q += __shfl_xor(q, 16, 64); q += __shfl_xor(q, 32, 64);
        if (quad == 0) { atomicAdd(&csum[col], s); atomicAdd(&csq[col], q); }
    }
    __syncthreads();
    if (tid < 128) {
        atomicAdd(&s2 [b * FDIM + tid], csum[tid]);
        atomicAdd(&s2q[b * FDIM + tid], csq[tid]);
    }
}

// ---------------------------------------------------------------- final in-place instance norm
__global__ void final_kernel(const float* __restrict__ gamma, const float* __restrict__ beta,
                             const float* __restrict__ s2, const float* __restrict__ s2q,
                             float* __restrict__ out) {
    size_t idx4 = ((size_t)blockIdx.x * 256 + threadIdx.x) * 4;
    int b  = (int)(idx4 >> 19);
    int g0 = (int)(idx4 & 127);
    float4 v = *reinterpret_cast<float4*>(&out[idx4]);
    float r[4] = {v.x, v.y, v.z, v.w};
#pragma unroll
    for (int j = 0; j < 4; j++) {
        int g      = g0 + j;
        float mean = s2[b * FDIM + g] * (1.f / LL);
        float var  = s2q[b * FDIM + g] * (1.f / LL) - mean * mean;
        float a    = gamma[g] * rsqrtf(var + EPSF);
        r[j]       = a * (r[j] - mean) + beta[g];
    }
    v.x = r[0]; v.y = r[1]; v.z = r[2]; v.w = r[3];
    *reinterpret_cast<float4*>(&out[idx4]) = v;
}

extern "C" void kernel_launch(void* const* d_in, const int* in_sizes, int n_in,
                              void* d_out, int out_size, void* d_ws, size_t ws_size,
                              hipStream_t stream) {
    const float* x     = (const float*)d_in[0];
    const float* q_w   = (const float*)d_in[1];
    const float* q_b   = (const float*)d_in[2];
    const float* k_w   = (const float*)d_in[3];
    const float* k_b   = (const float*)d_in[4];
    const float* ff_w  = (const float*)d_in[5];
    const float* ff_b  = (const float*)d_in[6];
    const float* gamma = (const float*)d_in[7];
    const float* beta  = (const float*)d_in[8];
    float* out = (float*)d_out;
    float* ws  = (float*)d_ws;
    unsigned short* attT = (unsigned short*)(ws + OFF_ATTT);

    hipMemsetAsync(d_ws, 0, (size_t)24576 * 4, stream);   // qsum..s2q

    coeff_kernel<<<16, 256, 0, stream>>>(q_w, q_b, k_w, k_b, ws);
    qk_kernel<<<dim3(16, 32), 256, 0, stream>>>(x, ws);
    att_kernel<<<32, 128, 0, stream>>>(ws, attT);
    gemm1_kernel<<<dim3(64, 32), 256, 0, stream>>>(x, attT, ws + OFF_X2,
                                                   ws + OFF_S1, ws + OFF_S1Q);
    gemm2_kernel<<<dim3(64, 32), 256, 0, stream>>>(ff_w, ff_b, gamma, beta,
                                                   ws + OFF_S1, ws + OFF_S1Q,
                                                   ws + OFF_X2, out,
                                                   ws + OFF_S2, ws + OFF_S2Q);
    final_kernel<<<16384, 256, 0, stream>>>(gamma, beta, ws + OFF_S2, ws + OFF_S2Q, out);
}